// Round 5
// baseline (354.790 us; speedup 1.0000x reference)
//
#include <hip/hip_runtime.h>
#include <hip/hip_bf16.h>

// ---------------------------------------------------------------------------
// DenseCorr2d_full — round 5.
//
// corr_g (v3): NO LDS. MFMA n = 16 x-positions strided 8 (x = 8n+s).  B-octet
//   for lane n = 16 B lane-contiguous row segment of a pre-padded bf16 copy
//   of tm (tmb, 2 parity copies for odd shifts) -> coalesced dwordx4 loads
//   (align-4 OK for global on gfx9+). A (templates) register-cached.
//   Per MFMA: 1 coalesced VMEM, 0 DS, 0 barriers.
// merge_mfma (v3): tile 8y x 16x, grid 1024, LDS 25.9 KB, lb(256,4)
//   -> ~4 blocks/CU (occupancy 2x round 4). W in blocked layout
//   Wb2[kk][cb=c/8][co][ci 8] so A-frag loads are lane-contiguous.
// ws: corrb bf16 NHWC [8][128][128][256] | Wb2 [9][32][64][8] | tmb [2][8][16][143][144]
// Fallback if ws too small for tmb: round-4 corr_mfma (LDS path).
// ---------------------------------------------------------------------------

typedef __attribute__((ext_vector_type(4))) float  f32x4;
typedef __attribute__((ext_vector_type(8))) short  bf16x8;

__device__ inline unsigned int pack_bf16x2(float a, float b) {
    unsigned int ua = __builtin_bit_cast(unsigned int, a);
    unsigned int ub = __builtin_bit_cast(unsigned int, b);
    ua = (ua + 0x7fffu + ((ua >> 16) & 1u)) >> 16;   // RNE
    ub = (ub + 0x7fffu + ((ub >> 16) & 1u)) >> 16;
    return ua | (ub << 16);
}
__device__ inline unsigned short cvt1(float f) {
    unsigned int u = __builtin_bit_cast(unsigned int, f);
    return (unsigned short)((u + 0x7fffu + ((u >> 16) & 1u)) >> 16);
}
__device__ inline bf16x8 load16_a4(const unsigned short* p) {
    bf16x8 v;
    __builtin_memcpy(&v, __builtin_assume_aligned(p, 4), 16);
    return v;
}

// ---------------- tm pre-pad: tmb[p][b][cm][r 143][c 144] bf16 --------------
// copy p: tmb[...][r][c] = bf16(tm[b][cm][min(r,127)][min(c+p,127)])
__global__ __launch_bounds__(256) void tmb_prep(
    const float* __restrict__ tm, unsigned short* __restrict__ tmb)
{
    int idx = (int)blockIdx.x * 256 + (int)threadIdx.x;   // < 5271552
    int c   = idx % 144;
    int rem = idx / 144;
    int r   = rem % 143;  rem /= 143;
    int cm  = rem & 15;   rem >>= 4;
    int b   = rem & 7;
    int p   = rem >> 3;
    int gy = r > 127 ? 127 : r;
    int gx = c + p; gx = gx > 127 ? 127 : gx;
    tmb[idx] = cvt1(tm[(((size_t)(b * 16 + cm)) << 14) + (gy << 7) + gx]);
}

// ---------------- Stage 1 v3: correlation, global-direct B-frags ------------
// Block: 256 thr = 4 waves; block <-> (b, cm-pair, 4-row y tile); wave w ->
// row y0+w, both cm of the pair. k = i*16+j; octet(kc,quad): i=2kc+qh,
// j=8jq+e. B-octet lane n = tmb[s&1][b][cm][y+i][8n+8jq+2(s>>1) .. +7].
__global__ __launch_bounds__(256) void corr_g(
    const float* __restrict__ tp, const unsigned short* __restrict__ tmb,
    unsigned short* __restrict__ corrb)
{
    const int t    = threadIdx.x;
    const int wave = t >> 6, lane = t & 63;
    const int n    = lane & 15, quad = lane >> 4;
    const int qh   = quad >> 1, jq = quad & 1;

    const int y    = ((int)blockIdx.x << 2) + wave;   // 0..127
    const int pair = (int)blockIdx.y & 7;
    const int b    = (int)blockIdx.y >> 3;

    // A-frags: tp[b][ct=n][i=2kc+qh][8jq .. +7], fp32 -> bf16 (register, once)
    bf16x8 bq[8];
    {
        const float* tpb = tp + (((size_t)(b * 16 + n)) << 8);
#pragma unroll
        for (int kc = 0; kc < 8; ++kc) {
            const float4* q = (const float4*)(tpb + (((2 * kc + qh) << 4) + (jq << 3)));
            float4 a = q[0], c4 = q[1];
            union { uint4 u; bf16x8 h; } cv;
            cv.u.x = pack_bf16x2(a.x, a.y);
            cv.u.y = pack_bf16x2(a.z, a.w);
            cv.u.z = pack_bf16x2(c4.x, c4.y);
            cv.u.w = pack_bf16x2(c4.z, c4.w);
            bq[kc] = cv.h;
        }
    }

    const size_t PLANE = 20592;                 // 143*144 shorts per (b,cm)
    const size_t PARS  = 128 * PLANE;           // parity-copy stride
    const size_t bcm0  = (size_t)(b * 16 + pair * 2) * PLANE;
    const int    colb  = (n << 3) + (jq << 3);  // 8n + 8jq

    f32x4 acc[2][8];                            // [cm2][s]
#pragma unroll
    for (int c2 = 0; c2 < 2; ++c2)
#pragma unroll
        for (int s = 0; s < 8; ++s) acc[c2][s] = (f32x4){0.f, 0.f, 0.f, 0.f};

#pragma unroll 1
    for (int kc = 0; kc < 8; ++kc) {
        const int row = y + 2 * kc + qh;
#pragma unroll
        for (int c2 = 0; c2 < 2; ++c2) {
            const unsigned short* base =
                tmb + bcm0 + (size_t)c2 * PLANE + (size_t)row * 144 + colb;
#pragma unroll
            for (int s = 0; s < 8; ++s) {
                const unsigned short* ps = base + (s & 1) * PARS + ((s >> 1) << 1);
                bf16x8 bf = load16_a4(ps);
                acc[c2][s] = __builtin_amdgcn_mfma_f32_16x16x32_bf16(
                    bq[kc], bf, acc[c2][s], 0, 0, 0);
            }
        }
    }

    // Epilogue: D[row=quad*4+r = ct][col=n]; x = 8n+s. 4 consecutive channels
    // per store; the cm-pair's two 32-B halves fill full 64-B sectors.
    const size_t posb = ((size_t)(b * 16384 + (y << 7)) << 8) + (pair << 5);
#pragma unroll
    for (int s = 0; s < 8; ++s) {
        const int x = (n << 3) + s;
#pragma unroll
        for (int c2 = 0; c2 < 2; ++c2) {
            uint2 v;
            v.x = pack_bf16x2(acc[c2][s][0], acc[c2][s][1]);
            v.y = pack_bf16x2(acc[c2][s][2], acc[c2][s][3]);
            *(uint2*)(corrb + posb + ((size_t)x << 8) + (c2 << 4) + (quad << 2)) = v;
        }
    }
}

// ---------------- W transform -> blocked Wb2[kk][cb 32][co 64][ci 8] --------
__global__ __launch_bounds__(256) void wt_kernel(
    const float* __restrict__ W, unsigned short* __restrict__ Wb2)
{
    int idx = (int)blockIdx.x * 256 + (int)threadIdx.x;   // < 147456
    int ci = idx & 7;
    int co = (idx >> 3) & 63;
    int cb = (idx >> 9) & 31;
    int kk = idx >> 14;
    int c  = (cb << 3) + ci;
    Wb2[idx] = cvt1(W[(size_t)co * 2304 + (size_t)c * 9 + kk]);
}

// ---------------- Stage 2 v3: 3x3 SAME merge conv, tile 8y x 16x ------------
__global__ __launch_bounds__(256, 4) void merge_mfma(
    const unsigned short* __restrict__ corrb, const unsigned short* __restrict__ Wb2,
    const float* __restrict__ bias, float* __restrict__ out)
{
    __shared__ __align__(16) unsigned short sm[10 * 18 * 72];  // 25920 B

    const int t    = threadIdx.x;
    const int wave = t >> 6, lane = t & 63;
    const int n    = lane & 15, quad = lane >> 4;
    const int x0   = (int)blockIdx.x << 4;   // 0..112
    const int y0   = (int)blockIdx.y << 3;   // 0..120
    const int b    = (int)blockIdx.z;

    f32x4 acc[4][2];                         // [co-tile][nt = y row]
#pragma unroll
    for (int a = 0; a < 4; ++a)
#pragma unroll
        for (int q = 0; q < 2; ++q) acc[a][q] = (f32x4){0.f, 0.f, 0.f, 0.f};

    const unsigned short* cb = corrb + ((size_t)b << 22);

#pragma unroll 1
    for (int c0 = 0; c0 < 256; c0 += 64) {
        __syncthreads();                     // guard prev-slab reads
        // stage halo patch: 10 rows x 18 cols x 64 ch = 1440 uint4
#pragma unroll
        for (int k = 0; k < 6; ++k) {
            int e = t + (k << 8);
            if (e < 1440) {
                int ci  = e & 7;
                int rem = e >> 3;
                int cc  = rem % 18, r = rem / 18;
                int gy = y0 - 1 + r, gx = x0 - 1 + cc;
                uint4 vv = {0u, 0u, 0u, 0u};
                if ((unsigned)gy < 128u && (unsigned)gx < 128u)
                    vv = *(const uint4*)(cb + (((size_t)((gy << 7) + gx)) << 8)
                                            + c0 + (ci << 3));
                *(uint4*)&sm[(r * 18 + cc) * 72 + (ci << 3)] = vv;
            }
        }
        __syncthreads();

#pragma unroll 1
        for (int kk = 0; kk < 9; ++kk) {
            const int dy = kk / 3, dx = kk - 3 * (kk / 3);
#pragma unroll
            for (int kc = 0; kc < 2; ++kc) {
                // af: Wb2[kk][(c0>>3)+kc*4+quad][ct*16+n][0..8) — lane-contiguous
                const unsigned short* wp = Wb2
                    + ((((size_t)kk * 32 + (c0 >> 3) + (kc << 2) + quad) << 6) + n) * 8;
                bf16x8 af[4];
#pragma unroll
                for (int ct = 0; ct < 4; ++ct)
                    af[ct] = *(const bf16x8*)(wp + (ct << 7));
#pragma unroll
                for (int nt = 0; nt < 2; ++nt) {
                    const int prow = 2 * wave + nt + dy;   // 0..9
                    const int pcol = n + dx;               // 0..17
                    bf16x8 bf = *(const bf16x8*)&sm[(prow * 18 + pcol) * 72
                                                    + (kc << 5) + (quad << 3)];
#pragma unroll
                    for (int ct = 0; ct < 4; ++ct)
                        acc[ct][nt] = __builtin_amdgcn_mfma_f32_16x16x32_bf16(
                            af[ct], bf, acc[ct][nt], 0, 0, 0);
                }
            }
        }
    }

    // Epilogue: D[row=quad*4+r = co][col=n = x], + bias
#pragma unroll
    for (int ct = 0; ct < 4; ++ct) {
#pragma unroll
        for (int nt = 0; nt < 2; ++nt) {
            const int y   = y0 + 2 * wave + nt;
            const int x   = x0 + n;
            const int co0 = (ct << 4) + (quad << 2);
            float* op = out + (((size_t)((b << 6) + co0) << 7) + y) * 128 + x;
#pragma unroll
            for (int r = 0; r < 4; ++r)
                op[(size_t)r << 14] = acc[ct][nt][r] + bias[co0 + r];
        }
    }
}

// ---------------- Fallback corr (round 4 LDS path, used if ws too small) ----
__global__ __launch_bounds__(256) void corr_mfma(
    const float* __restrict__ tp, const float* __restrict__ tm,
    unsigned short* __restrict__ corrb)
{
    __shared__ __align__(16) unsigned short smA[2 * 2 * 31 * 82];

    const int t    = threadIdx.x;
    const int wave = t >> 6, lane = t & 63;
    const int n    = lane & 15, quad = lane >> 4;
    const int qh   = quad >> 1, jq = quad & 1;

    const int xh   = (int)blockIdx.x & 1;
    const int y0   = ((int)blockIdx.x >> 1) << 4;
    const int pair = (int)blockIdx.y & 7;
    const int b    = (int)blockIdx.y >> 3;
    const int xg0  = xh << 6;

    for (int cm2 = 0; cm2 < 2; ++cm2) {
        const float* src = tm + (((size_t)(b * 16 + pair * 2 + cm2)) << 14);
        for (int e = t; e < 31 * 80; e += 256) {
            int r = e / 80, c = e - r * 80;
            int gy = y0 + r;  gy = gy > 127 ? 127 : gy;
            int gx = xg0 + c; gx = gx > 127 ? 127 : gx;
            unsigned short h = cvt1(src[(gy << 7) + gx]);
            smA[((cm2 * 2 + 0) * 31 + r) * 82 + c] = h;
            if (c > 0)
                smA[((cm2 * 2 + 1) * 31 + r) * 82 + (c - 1)] = h;
        }
    }
    __syncthreads();

    bf16x8 bq[8];
    {
        const float* tpb = tp + (((size_t)(b * 16 + n)) << 8);
#pragma unroll
        for (int kc = 0; kc < 8; ++kc) {
            const float4* q = (const float4*)(tpb + (((2 * kc + qh) << 4) + (jq << 3)));
            float4 a = q[0], c4 = q[1];
            union { uint4 u; bf16x8 h; } cv;
            cv.u.x = pack_bf16x2(a.x, a.y);
            cv.u.y = pack_bf16x2(a.z, a.w);
            cv.u.z = pack_bf16x2(c4.x, c4.y);
            cv.u.w = pack_bf16x2(c4.z, c4.w);
            bq[kc] = cv.h;
        }
    }

    const unsigned* smAd = (const unsigned*)smA;
    const int PITCH = 41, PLANE = 31 * 41;

#pragma unroll 1
    for (int it = 0; it < 8; ++it) {
        const int lxa = (wave << 4) + (it << 1);
        const int D00 = (n + qh) * PITCH + ((lxa + (jq << 3)) >> 1);

        f32x4 acc[4];
#pragma unroll
        for (int q = 0; q < 4; ++q) acc[q] = (f32x4){0.f, 0.f, 0.f, 0.f};

#pragma unroll
        for (int kc = 0; kc < 8; ++kc) {
            const int dof = D00 + kc * 82;
#pragma unroll
            for (int ch = 0; ch < 4; ++ch) {
                const int d = dof + ch * PLANE;
                union { uint4 u; bf16x8 h; } fr;
                fr.u.x = smAd[d];     fr.u.y = smAd[d + 1];
                fr.u.z = smAd[d + 2]; fr.u.w = smAd[d + 3];
                const int ai = ((ch & 1) << 1) | (ch >> 1);
                acc[ai] = __builtin_amdgcn_mfma_f32_16x16x32_bf16(
                    bq[kc], fr.h, acc[ai], 0, 0, 0);
            }
        }

        const int y = y0 + n;
#pragma unroll
        for (int ai = 0; ai < 4; ++ai) {
            const int par = ai >> 1, cm2 = ai & 1;
            const int x   = xg0 + lxa + par;
            uint2 v;
            v.x = pack_bf16x2(acc[ai][0], acc[ai][1]);
            v.y = pack_bf16x2(acc[ai][2], acc[ai][3]);
            unsigned short* dst = corrb
                + (((size_t)(b * 16384 + (y << 7) + x)) << 8)
                + (pair << 5) + (cm2 << 4) + (quad << 2);
            *(uint2*)dst = v;
        }
    }
}

extern "C" void kernel_launch(void* const* d_in, const int* in_sizes, int n_in,
                              void* d_out, int out_size, void* d_ws, size_t ws_size,
                              hipStream_t stream)
{
    const float* tp   = (const float*)d_in[0];   // template [8,16,16,16]
    const float* tm   = (const float*)d_in[1];   // tomatch  [8,16,128,128]
    const float* Wt   = (const float*)d_in[2];   // W        [64,256,3,3]
    const float* bias = (const float*)d_in[3];   // b        [64]
    float* out = (float*)d_out;                  // [8,64,128,128] fp32

    unsigned short* corrb = (unsigned short*)d_ws;              // 67,108,864 B
    unsigned short* Wb2   = corrb + (size_t)8 * 16384 * 256;    //    294,912 B
    unsigned short* tmb   = Wb2 + (size_t)9 * 32 * 64 * 8;      // 10,543,104 B

    const size_t need_v3 = (size_t)67108864 + 294912 + 10543104;
    const bool use_v3 = (ws_size >= need_v3);    // constant per session

    if (use_v3) {
        tmb_prep<<<dim3(20592), dim3(256), 0, stream>>>(tm, tmb);
        corr_g<<<dim3(32, 64), dim3(256), 0, stream>>>(tp, tmb, corrb);
    } else {
        corr_mfma<<<dim3(16, 64), dim3(256), 0, stream>>>(tp, tm, corrb);
    }
    wt_kernel<<<dim3(576), dim3(256), 0, stream>>>(Wt, Wb2);
    merge_mfma<<<dim3(8, 16, 8), dim3(256), 0, stream>>>(corrb, Wb2, bias, out);
}